// Round 10
// baseline (533.170 us; speedup 1.0000x reference)
//
#include <hip/hip_runtime.h>
#include <math.h>

// SOM2dLayer forward: BMU indices + quantization error.
// X[4096,64] f32, W[65536,64] f32 -> out f32: [B*2] (y,x) then [B] qe.
//
// acc'(row,n) = bf16dot(x,w) + w2c[n], w2c = -0.5*sum(w^2); s = -2*acc'.
// min_n s  <=>  max_n acc'.
//   k_prep:    fp32 -> bf16 copies (W and X) + exact w2c
//   k_screen0: bf16 MFMA screen, barrier-free wave-private 3-slot LDS ring,
//              FULLY UNROLLED 16-panel loop (static slots, static waits),
//              all per-lane w2c preloaded to regs, c folded into MFMA C-init.
//              Emits pm[row][256] exact f32 coarse max (sub = wave 8-panel
//              chunk) and pmf[fine][row] round-UP bf16 fine max (16 n).
//   k_rescore: thr = max(pm)-MARG; qualifying coarse subs -> fine subs ->
//              exact fp32 rescore (16 n each); argmin, first-index tie-break;
//              qe = sqrt(max(x2+s,0)).
// Round-up bf16 pmf is conservative -> candidate superset, no false
// negatives. No atomics, no barriers -> deterministic.

typedef short  bf16x8 __attribute__((ext_vector_type(8)));
typedef float  f32x4  __attribute__((ext_vector_type(4)));
typedef unsigned short u16;
typedef unsigned short u16x4 __attribute__((ext_vector_type(4)));

constexpr int D     = 64;
constexpr int NW    = 65536;
constexpr int B     = 4096;
constexpr int NSUB  = 256;             // coarse subs (256 n each, wave-chunk)
constexpr int NFINE = NW / 16;         // 4096 fine subs (16 n each)
constexpr float MARG_HALF = 0.15f;     // bf16 screen margin (acc' scale)

constexpr int STRIPS   = 32;
constexpr int STRIP_N  = NW / STRIPS;  // 2048 n per block (16 panels of 128)
constexpr int ROWS_BLK = 128;

__device__ inline u16 bf16u(float f) {
    union { float f; unsigned u; } v; v.f = f;
    unsigned b = v.u;
    b += 0x7fffu + ((b >> 16) & 1u);   // RNE, finite inputs only
    return (u16)(b >> 16);
}

__device__ inline u16 bf16up(float f) {   // round toward +inf (conservative max)
    union { float f; unsigned u; } v; v.f = f;
    unsigned h = v.u >> 16;
    if ((v.u & 0xFFFFu) && !(v.u >> 31)) h += 1;
    return (u16)h;
}

__device__ __forceinline__ void gload_lds16(const void* g, void* l) {
    __builtin_amdgcn_global_load_lds(
        (const __attribute__((address_space(1))) unsigned int*)g,
        (__attribute__((address_space(3))) unsigned int*)l, 16, 0, 0);
}

// ---- prep: W,X -> bf16 + w2c (fused, one launch) --------------------------
__global__ __launch_bounds__(256) void k_prep(const float* __restrict__ w,
                                              const float* __restrict__ x,
                                              u16* __restrict__ whi,
                                              u16* __restrict__ xhi,
                                              float* __restrict__ w2c) {
    const int idx = blockIdx.x * 256 + threadIdx.x;
    if (idx < NW) {
        const float4* wr = reinterpret_cast<const float4*>(w + (size_t)idx * D);
        u16* orow = whi + (size_t)idx * D;
        float a0 = 0.f, a1 = 0.f, a2 = 0.f, a3 = 0.f;
#pragma unroll
        for (int h = 0; h < 8; ++h) {
            float4 v0 = wr[2 * h], v1 = wr[2 * h + 1];
            a0 = fmaf(v0.x, v0.x, a0); a1 = fmaf(v0.y, v0.y, a1);
            a2 = fmaf(v0.z, v0.z, a2); a3 = fmaf(v0.w, v0.w, a3);
            a0 = fmaf(v1.x, v1.x, a0); a1 = fmaf(v1.y, v1.y, a1);
            a2 = fmaf(v1.z, v1.z, a2); a3 = fmaf(v1.w, v1.w, a3);
            bf16x8 o = {(short)bf16u(v0.x), (short)bf16u(v0.y),
                        (short)bf16u(v0.z), (short)bf16u(v0.w),
                        (short)bf16u(v1.x), (short)bf16u(v1.y),
                        (short)bf16u(v1.z), (short)bf16u(v1.w)};
            *reinterpret_cast<bf16x8*>(orow + 8 * h) = o;
        }
        w2c[idx] = -0.5f * ((a0 + a1) + (a2 + a3));
    } else {
        const int r = idx - NW;
        const float4* xr = reinterpret_cast<const float4*>(x + (size_t)r * D);
        u16* orow = xhi + (size_t)r * D;
#pragma unroll
        for (int h = 0; h < 8; ++h) {
            float4 v0 = xr[2 * h], v1 = xr[2 * h + 1];
            bf16x8 o = {(short)bf16u(v0.x), (short)bf16u(v0.y),
                        (short)bf16u(v0.z), (short)bf16u(v0.w),
                        (short)bf16u(v1.x), (short)bf16u(v1.y),
                        (short)bf16u(v1.z), (short)bf16u(v1.w)};
            *reinterpret_cast<bf16x8*>(orow + 8 * h) = o;
        }
    }
}

// ---- MFMA screen: barrier-free, wave-private, FULLY STATIC ----------------
// Block: 4 waves x 128 rows, strip of 2048 n = 16 panels of 128 n.
// Wave wv owns band [wv*32, wv*32+32) of every panel (4 KB LDS slice).
// coarse sub s = strip*8 + ch*4 + wv  (ch = 8-panel chunk): the wave's 256 n
//   of that chunk. fine sub (s,col): n at fixed col over {8 panels x 2 t}.
template <int WRITE_FINE>
__global__ __launch_bounds__(256, 3) void k_screen0(
        const u16* __restrict__ whi, const u16* __restrict__ xhi,
        const float* __restrict__ w2c, float* __restrict__ pm,
        u16* __restrict__ pmf) {
    __shared__ __align__(16) char smem[4][3][4096];   // [wave][slot][4KB]
    const int bid   = blockIdx.x;
    const int strip = bid & 31;          // all blocks of a strip on XCD strip%8
    const int rbk   = bid >> 5;
    const int wv    = threadIdx.x >> 6;
    const int lane  = threadIdx.x & 63;
    const int col   = lane & 15;
    const int kg    = lane >> 4;
    const int row0  = rbk * ROWS_BLK;
    const int N0    = strip * STRIP_N;

    // all 32 per-lane c constants (panel p, tile t: m = 2p+t), static indices
    float c32[32];
#pragma unroll
    for (int m = 0; m < 32; ++m)
        c32[m] = w2c[N0 + (m >> 1) * 128 + wv * 32 + (m & 1) * 16 + col];

    // A fragments (x rows), resident whole kernel: 8 rg x 2 k-halves.
    bf16x8 a[8][2];
#pragma unroll
    for (int rg = 0; rg < 8; ++rg)
#pragma unroll
        for (int h = 0; h < 2; ++h)
            a[rg][h] = *reinterpret_cast<const bf16x8*>(
                xhi + (size_t)(row0 + rg * 16 + col) * D + h * 32 + kg * 8);

    // staging: LDS linear o <- global (o ^ ((o>>7&7)<<4)), band-local.
    const char* wband = (const char*)whi + (size_t)(N0 + wv * 32) * 128;
    unsigned soff[4];
#pragma unroll
    for (int i = 0; i < 4; ++i) {
        unsigned o = (unsigned)(i * 64 + lane) * 16;
        soff[i] = o ^ (((o >> 7) & 7u) << 4);
    }

    const unsigned msk = (unsigned)(col & 7) << 4;   // read-side swizzle
    float mx[8][4];
#pragma unroll
    for (int rg = 0; rg < 8; ++rg)
#pragma unroll
        for (int r = 0; r < 4; ++r) mx[rg][r] = -3.4e38f;

    // prologue stages (slots 0,1)
#pragma unroll
    for (int i = 0; i < 4; ++i)
        gload_lds16(wband + soff[i], &smem[wv][0][i * 1024]);
#pragma unroll
    for (int i = 0; i < 4; ++i)
        gload_lds16(wband + 16384 + soff[i], &smem[wv][1][i * 1024]);

#pragma unroll
    for (int p = 0; p < 16; ++p) {
        if (p + 2 < 16) {   // stage panel p+2 into slot (p+2)%3 (static)
            const char* g = wband + (size_t)(p + 2) * 16384;
            char* d = &smem[wv][(p + 2) % 3][0];
#pragma unroll
            for (int i = 0; i < 4; ++i)
                gload_lds16(g + soff[i], d + i * 1024);
        }
        // counted waits: S(p) complete with S(p+1),S(p+2) left in flight
        if (p <= 13)      asm volatile("s_waitcnt vmcnt(8)" ::: "memory");
        else if (p == 14) asm volatile("s_waitcnt vmcnt(4)" ::: "memory");
        else              asm volatile("s_waitcnt vmcnt(0)" ::: "memory");

        const char* buf = &smem[wv][p % 3][0];
#pragma unroll
        for (int t = 0; t < 2; ++t) {
            const unsigned g = (unsigned)(t * 16 + col) * 128 + kg * 16;
            const bf16x8 b0 = *reinterpret_cast<const bf16x8*>(buf + (g ^ msk));
            const bf16x8 b1 = *reinterpret_cast<const bf16x8*>(buf + ((g + 64) ^ msk));
            const float c = c32[p * 2 + t];
            const f32x4 cq = {c, c, c, c};
#pragma unroll
            for (int rg = 0; rg < 8; ++rg) {
                f32x4 acc = __builtin_amdgcn_mfma_f32_16x16x32_bf16(a[rg][0], b0, cq, 0, 0, 0);
                acc = __builtin_amdgcn_mfma_f32_16x16x32_bf16(a[rg][1], b1, acc, 0, 0, 0);
                mx[rg][0] = fmaxf(mx[rg][0], acc[0]);
                mx[rg][1] = fmaxf(mx[rg][1], acc[1]);
                mx[rg][2] = fmaxf(mx[rg][2], acc[2]);
                mx[rg][3] = fmaxf(mx[rg][3], acc[3]);
            }
        }

        if ((p & 7) == 7) {   // chunk boundary: wave's 256 n done
            const int ch = p >> 3;
            const int s  = strip * 8 + ch * 4 + wv;   // coarse sub id

            if (WRITE_FINE) {  // per-lane fine maxes, no shuffles
                const int f = s * 16 + col;
#pragma unroll
                for (int rg = 0; rg < 8; ++rg) {
                    u16x4 h4 = {bf16up(mx[rg][0]), bf16up(mx[rg][1]),
                                bf16up(mx[rg][2]), bf16up(mx[rg][3])};
                    *reinterpret_cast<u16x4*>(
                        pmf + (size_t)f * B + row0 + rg * 16 + kg * 4) = h4;
                }
            }

#pragma unroll
            for (int rg = 0; rg < 8; ++rg) {
                float v0 = mx[rg][0], v1 = mx[rg][1], v2 = mx[rg][2], v3 = mx[rg][3];
#pragma unroll
                for (int sh = 1; sh < 16; sh <<= 1) {
                    v0 = fmaxf(v0, __shfl_xor(v0, sh, 64));
                    v1 = fmaxf(v1, __shfl_xor(v1, sh, 64));
                    v2 = fmaxf(v2, __shfl_xor(v2, sh, 64));
                    v3 = fmaxf(v3, __shfl_xor(v3, sh, 64));
                }
                float vv = v0;
                vv = (col == 1) ? v1 : vv;
                vv = (col == 2) ? v2 : vv;
                vv = (col == 3) ? v3 : vv;
                if (col < 4)
                    pm[(size_t)(row0 + rg * 16 + kg * 4 + col) * NSUB + s] = vv;
                mx[rg][0] = -3.4e38f; mx[rg][1] = -3.4e38f;
                mx[rg][2] = -3.4e38f; mx[rg][3] = -3.4e38f;
            }
        }
    }
}

// ---- exact fp32 rescore + output (one wave per row) -----------------------
// sub s -> strip = s>>3, ch = (s&7)>>2, wvv = s&3:
//   base = strip*2048 + ch*1024 + wvv*32
//   n(pp,t,c) = base + pp*128 + t*16 + c   (pp 0..7, t 0..1, c 0..15)
// fine (s, c): j = 0..15 -> n = base + (j>>1)*128 + (j&1)*16 + c
template <int FINE>
__global__ __launch_bounds__(256) void k_rescore(
        const float* __restrict__ x, const float* __restrict__ w,
        const float* __restrict__ w2c, const float* __restrict__ pm,
        const u16* __restrict__ pmf, float* __restrict__ out) {
    const int wv   = threadIdx.x >> 6;
    const int lane = threadIdx.x & 63;
    const int row  = blockIdx.x * 4 + wv;

    float pv[4];
#pragma unroll
    for (int it = 0; it < 4; ++it)
        pv[it] = pm[(size_t)row * NSUB + it * 64 + lane];
    float gm = fmaxf(fmaxf(pv[0], pv[1]), fmaxf(pv[2], pv[3]));
#pragma unroll
    for (int s = 1; s < 64; s <<= 1) gm = fmaxf(gm, __shfl_xor(gm, s, 64));
    const float thr = gm - MARG_HALF;

    const float4* xr = reinterpret_cast<const float4*>(x + (size_t)row * D);
    float4 xq[16];
#pragma unroll
    for (int q = 0; q < 16; ++q) xq[q] = xr[q];

    float bestv = 3.4e38f;
    int   besti = 0x7fffffff;

#pragma unroll
    for (int it = 0; it < 4; ++it) {
        unsigned long long bm = __ballot(pv[it] >= thr);
        while (bm) {
            int sb = __ffsll(bm) - 1;
            bm &= bm - 1;
            int sub = it * 64 + sb;
            int base = (sub >> 3) * 2048 + (((sub >> 2) & 1)) * 1024 + (sub & 3) * 32;

            if (FINE) {
                // 16 fine bf16 (round-up) maxes of this coarse sub
                float fv = -3.4e38f;
                if (lane < 16) {
                    union { unsigned u; float f; } c;
                    c.u = (unsigned)pmf[(size_t)(sub * 16 + lane) * B + row] << 16;
                    fv = c.f;
                }
                unsigned long long fm = __ballot(fv >= thr);   // bits 0..15
                while (fm) {
                    int colq = __ffsll(fm) - 1;
                    fm &= fm - 1;
                    // fine sub n-set: base + (j>>1)*128 + (j&1)*16 + colq
                    int j = lane & 15, q = lane >> 4;
                    int n = base + (j >> 1) * 128 + (j & 1) * 16 + colq;
                    const float4* wr = reinterpret_cast<const float4*>(w + (size_t)n * D);
                    float d0 = 0.f, d1 = 0.f, d2 = 0.f, d3 = 0.f;
#pragma unroll
                    for (int k = 0; k < 4; ++k) {
                        float4 wq = wr[q * 4 + k];
                        float4 xv = xq[q * 4 + k];
                        d0 = fmaf(xv.x, wq.x, d0); d1 = fmaf(xv.y, wq.y, d1);
                        d2 = fmaf(xv.z, wq.z, d2); d3 = fmaf(xv.w, wq.w, d3);
                    }
                    float d = (d0 + d1) + (d2 + d3);
                    d += __shfl_xor(d, 16, 64);
                    d += __shfl_xor(d, 32, 64);      // all 4 copies hold full dot
                    float val = -2.f * (d + w2c[n]);  // == w2 - 2*x.w exact fp32
                    if (val < bestv || (val == bestv && n < besti)) { bestv = val; besti = n; }
                }
            } else {
#pragma unroll
                for (int q4 = 0; q4 < 4; ++q4) {
                    int idx = q4 * 64 + lane;
                    int n = base + (idx >> 5) * 128 + (idx & 31);
                    const float4* wr = reinterpret_cast<const float4*>(w + (size_t)n * D);
                    float d0 = 0.f, d1 = 0.f, d2 = 0.f, d3 = 0.f;
#pragma unroll
                    for (int q = 0; q < 16; ++q) {
                        float4 wq = wr[q];
                        d0 = fmaf(xq[q].x, wq.x, d0);
                        d1 = fmaf(xq[q].y, wq.y, d1);
                        d2 = fmaf(xq[q].z, wq.z, d2);
                        d3 = fmaf(xq[q].w, wq.w, d3);
                    }
                    float dot = (d0 + d1) + (d2 + d3);
                    float val = -2.f * (dot + w2c[n]);
                    if (val < bestv || (val == bestv && n < besti)) { bestv = val; besti = n; }
                }
            }
        }
    }
#pragma unroll
    for (int s = 1; s < 64; s <<= 1) {
        float ov = __shfl_xor(bestv, s, 64);
        int   oi = __shfl_xor(besti, s, 64);
        if (ov < bestv || (ov == bestv && oi < besti)) { bestv = ov; besti = oi; }
    }
    if (lane == 0) {
        float a0 = 0.f, a1 = 0.f, a2 = 0.f, a3 = 0.f;
#pragma unroll
        for (int q = 0; q < 16; ++q) {
            a0 = fmaf(xq[q].x, xq[q].x, a0);
            a1 = fmaf(xq[q].y, xq[q].y, a1);
            a2 = fmaf(xq[q].z, xq[q].z, a2);
            a3 = fmaf(xq[q].w, xq[q].w, a3);
        }
        float x2 = (a0 + a1) + (a2 + a3);
        float d2f = x2 + bestv;
        if (d2f < 0.f) d2f = 0.f;
        out[row * 2 + 0] = (float)(besti >> 8);    // bmu_y
        out[row * 2 + 1] = (float)(besti & 255);   // bmu_x
        out[2 * B + row] = sqrtf(d2f);
    }
}

// ---- fallback (round-3 proven path, ~1.3 MB ws) ---------------------------
__global__ __launch_bounds__(256) void fb_w2(const float* __restrict__ w,
                                             float* __restrict__ w2) {
    int n = blockIdx.x * 256 + threadIdx.x;
    const float4* wr = reinterpret_cast<const float4*>(w + (size_t)n * D);
    float a0 = 0.f, a1 = 0.f, a2 = 0.f, a3 = 0.f;
#pragma unroll
    for (int q = 0; q < 16; ++q) {
        float4 v = wr[q];
        a0 = fmaf(v.x, v.x, a0); a1 = fmaf(v.y, v.y, a1);
        a2 = fmaf(v.z, v.z, a2); a3 = fmaf(v.w, v.w, a3);
    }
    w2[n] = (a0 + a1) + (a2 + a3);
}

__global__ __launch_bounds__(256) void fb_main(const float* __restrict__ x,
                                               const float* __restrict__ w,
                                               const float* __restrict__ w2,
                                               float* __restrict__ ps,
                                               int* __restrict__ pi) {
    constexpr int NSTRIP = NW / 32;
    const int rb    = blockIdx.x & 15;
    const int strip = blockIdx.x >> 4;
    const int row   = rb * 256 + threadIdx.x;
    float xr[D];
    const float4* xrow = reinterpret_cast<const float4*>(x + (size_t)row * D);
#pragma unroll
    for (int q = 0; q < 16; ++q) {
        float4 v = xrow[q];
        xr[q * 4 + 0] = v.x; xr[q * 4 + 1] = v.y;
        xr[q * 4 + 2] = v.z; xr[q * 4 + 3] = v.w;
    }
    float best = 3.4e38f; int bidx = 0;
    const int n0 = strip * NSTRIP, n1 = n0 + NSTRIP;
    for (int n = n0; n < n1; ++n) {
        const float* wr = w + (size_t)n * D;
        float a0 = 0.f, a1 = 0.f, a2 = 0.f, a3 = 0.f;
#pragma unroll
        for (int d = 0; d < D; d += 4) {
            a0 = fmaf(xr[d + 0], wr[d + 0], a0);
            a1 = fmaf(xr[d + 1], wr[d + 1], a1);
            a2 = fmaf(xr[d + 2], wr[d + 2], a2);
            a3 = fmaf(xr[d + 3], wr[d + 3], a3);
        }
        float s = fmaf(-2.f, (a0 + a1) + (a2 + a3), w2[n]);
        if (s < best) { best = s; bidx = n; }
    }
    ps[(size_t)strip * B + row] = best;
    pi[(size_t)strip * B + row] = bidx;
}

__global__ __launch_bounds__(256) void fb_merge(const float* __restrict__ x,
                                                const float* __restrict__ ps,
                                                const int* __restrict__ pi,
                                                float* __restrict__ out) {
    int row = blockIdx.x * 256 + threadIdx.x;
    float bs = 3.5e38f; int bi = 0;
    for (int t = 0; t < 32; ++t) {
        float s = ps[(size_t)t * B + row];
        int   i = pi[(size_t)t * B + row];
        if (s < bs || (s == bs && i < bi)) { bs = s; bi = i; }
    }
    const float4* xrow = reinterpret_cast<const float4*>(x + (size_t)row * D);
    float a0 = 0.f, a1 = 0.f, a2 = 0.f, a3 = 0.f;
#pragma unroll
    for (int q = 0; q < 16; ++q) {
        float4 v = xrow[q];
        a0 = fmaf(v.x, v.x, a0); a1 = fmaf(v.y, v.y, a1);
        a2 = fmaf(v.z, v.z, a2); a3 = fmaf(v.w, v.w, a3);
    }
    float x2 = (a0 + a1) + (a2 + a3);
    float d2 = x2 + bs;
    if (d2 < 0.f) d2 = 0.f;
    out[row * 2 + 0] = (float)(bi >> 8);
    out[row * 2 + 1] = (float)(bi & 255);
    out[2 * B + row] = sqrtf(d2);
}

// ---------------------------------------------------------------------------
extern "C" void kernel_launch(void* const* d_in, const int* in_sizes, int n_in,
                              void* d_out, int out_size, void* d_ws, size_t ws_size,
                              hipStream_t stream) {
    const float* x = (const float*)d_in[0];   // [B, D]
    const float* w = (const float*)d_in[1];   // [NW, D]
    float* out = (float*)d_out;

    const size_t whi_sz = (size_t)NW * D * 2;        // 8 MB
    const size_t xhi_sz = (size_t)B * D * 2;         // 512 KB
    const size_t w2c_sz = (size_t)NW * 4;            // 256 KB
    const size_t pm_sz  = (size_t)B * NSUB * 4;      // 4 MB
    const size_t pmf_sz = (size_t)NFINE * B * 2;     // 33.5 MB
    const size_t need_c = whi_sz + xhi_sz + w2c_sz + pm_sz;
    const size_t need_f = need_c + pmf_sz;

    if (ws_size >= need_c) {
        char* p = (char*)d_ws;
        u16*   whi = (u16*)p;   p += whi_sz;
        u16*   xhi = (u16*)p;   p += xhi_sz;
        float* w2c = (float*)p; p += w2c_sz;
        float* pm  = (float*)p; p += pm_sz;
        u16*   pmf = (u16*)p;

        k_prep<<<(NW + B) / 256, 256, 0, stream>>>(w, x, whi, xhi, w2c);
        if (ws_size >= need_f) {
            k_screen0<1><<<STRIPS * (B / ROWS_BLK), 256, 0, stream>>>(whi, xhi, w2c, pm, pmf);
            k_rescore<1><<<B / 4, 256, 0, stream>>>(x, w, w2c, pm, pmf, out);
        } else {
            k_screen0<0><<<STRIPS * (B / ROWS_BLK), 256, 0, stream>>>(whi, xhi, w2c, pm, pmf);
            k_rescore<0><<<B / 4, 256, 0, stream>>>(x, w, w2c, pm, pmf, out);
        }
    } else {
        float* w2 = (float*)d_ws;
        float* ps = w2 + NW;
        int*   pi = (int*)(ps + (size_t)32 * B);
        fb_w2<<<NW / 256, 256, 0, stream>>>(w, w2);
        fb_main<<<16 * 32, 256, 0, stream>>>(x, w, w2, ps, pi);
        fb_merge<<<B / 256, 256, 0, stream>>>(x, ps, pi, out);
    }
}

// Round 11
// 370.755 us; speedup vs baseline: 1.4381x; 1.4381x over previous
//
#include <hip/hip_runtime.h>
#include <math.h>

// SOM2dLayer forward: BMU indices + quantization error.
// X[4096,64] f32, W[65536,64] f32 -> out f32: [B*2] (y,x) then [B] qe.
//
// acc'(row,n) = bf16dot(x,w) + w2c[n], w2c = -0.5*sum(w^2); s = -2*acc'.
// min_n s  <=>  max_n acc'.
//   k_prep:    fp32 -> bf16 copies (W and X) + exact w2c
//   k_screen0: bf16 MFMA screen. Round-11 structure = round-7 (best so far,
//              block-staged LDS + barrier pipeline) with SINGLE 32KB buffer
//              and 2x grid: 4 blocks/CU so per-panel barrier drains hide
//              across blocks (TLP), not within one (ILP attempts r8-r10 all
//              lost to latency or spill). Emits:
//                pm [row][256]  exact f32 max per coarse sub (256 n)
//                pmf[fine][row] round-UP bf16 max per fine sub (16 n)
//   k_rescore: thr = max(pm)-MARG; qualifying coarse subs -> fine subs ->
//              exact fp32 rescore (16 n each); argmin, first-index tie-break;
//              qe = sqrt(max(x2+s,0)).
// Round-up bf16 pmf is conservative -> candidate superset, no false
// negatives. No atomics -> deterministic.

typedef short  bf16x8 __attribute__((ext_vector_type(8)));
typedef float  f32x4  __attribute__((ext_vector_type(4)));
typedef unsigned short u16;
typedef unsigned short u16x4 __attribute__((ext_vector_type(4)));

constexpr int D     = 64;
constexpr int NW    = 65536;
constexpr int B     = 4096;
constexpr int NSUB  = 256;             // coarse subs (256 n each)
constexpr int NFINE = NW / 16;         // 4096 fine subs (16 n each)
constexpr float MARG_HALF = 0.15f;     // bf16 screen margin (acc' scale)

constexpr int STRIPS   = 32;
constexpr int STRIP_N  = NW / STRIPS;  // 2048 n per strip = 8 panels of 256
constexpr int PANELS   = 8;
constexpr int ROWS_BLK = 128;

__device__ inline u16 bf16u(float f) {
    union { float f; unsigned u; } v; v.f = f;
    unsigned b = v.u;
    b += 0x7fffu + ((b >> 16) & 1u);   // RNE, finite inputs only
    return (u16)(b >> 16);
}

__device__ inline u16 bf16up(float f) {   // round toward +inf (conservative max)
    union { float f; unsigned u; } v; v.f = f;
    unsigned h = v.u >> 16;
    if ((v.u & 0xFFFFu) && !(v.u >> 31)) h += 1;
    return (u16)h;
}

__device__ __forceinline__ void gload_lds16(const void* g, void* l) {
    __builtin_amdgcn_global_load_lds(
        (const __attribute__((address_space(1))) unsigned int*)g,
        (__attribute__((address_space(3))) unsigned int*)l, 16, 0, 0);
}

// ---- prep: W,X -> bf16 + w2c (fused, one launch) --------------------------
__global__ __launch_bounds__(256) void k_prep(const float* __restrict__ w,
                                              const float* __restrict__ x,
                                              u16* __restrict__ whi,
                                              u16* __restrict__ xhi,
                                              float* __restrict__ w2c) {
    const int idx = blockIdx.x * 256 + threadIdx.x;
    if (idx < NW) {
        const float4* wr = reinterpret_cast<const float4*>(w + (size_t)idx * D);
        u16* orow = whi + (size_t)idx * D;
        float a0 = 0.f, a1 = 0.f, a2 = 0.f, a3 = 0.f;
#pragma unroll
        for (int h = 0; h < 8; ++h) {
            float4 v0 = wr[2 * h], v1 = wr[2 * h + 1];
            a0 = fmaf(v0.x, v0.x, a0); a1 = fmaf(v0.y, v0.y, a1);
            a2 = fmaf(v0.z, v0.z, a2); a3 = fmaf(v0.w, v0.w, a3);
            a0 = fmaf(v1.x, v1.x, a0); a1 = fmaf(v1.y, v1.y, a1);
            a2 = fmaf(v1.z, v1.z, a2); a3 = fmaf(v1.w, v1.w, a3);
            bf16x8 o = {(short)bf16u(v0.x), (short)bf16u(v0.y),
                        (short)bf16u(v0.z), (short)bf16u(v0.w),
                        (short)bf16u(v1.x), (short)bf16u(v1.y),
                        (short)bf16u(v1.z), (short)bf16u(v1.w)};
            *reinterpret_cast<bf16x8*>(orow + 8 * h) = o;
        }
        w2c[idx] = -0.5f * ((a0 + a1) + (a2 + a3));
    } else {
        const int r = idx - NW;
        const float4* xr = reinterpret_cast<const float4*>(x + (size_t)r * D);
        u16* orow = xhi + (size_t)r * D;
#pragma unroll
        for (int h = 0; h < 8; ++h) {
            float4 v0 = xr[2 * h], v1 = xr[2 * h + 1];
            bf16x8 o = {(short)bf16u(v0.x), (short)bf16u(v0.y),
                        (short)bf16u(v0.z), (short)bf16u(v0.w),
                        (short)bf16u(v1.x), (short)bf16u(v1.y),
                        (short)bf16u(v1.z), (short)bf16u(v1.w)};
            *reinterpret_cast<bf16x8*>(orow + 8 * h) = o;
        }
    }
}

// ---- MFMA screen: single-buffer LDS, 4 blocks/CU --------------------------
// Block: 4 waves x 128 rows, strip = 2048 n = 8 panels of 256 n.
// Wave wv computes n-range [wv*64, wv*64+64) of each panel (4 tiles of 16).
// coarse sub s = strip*8 + chunk*4 + wv, chunk = p>>2 (4 panels = 256 n/wave)
// fine sub (s,col): n = strip*2048 + (chunk*4+p')*256 + wv*64 + t*16 + col,
//   j = p'*4 + t  (j = 0..15).
template <int WRITE_FINE>
__global__ __launch_bounds__(256, 4) void k_screen0(
        const u16* __restrict__ whi, const u16* __restrict__ xhi,
        const float* __restrict__ w2c, float* __restrict__ pm,
        u16* __restrict__ pmf) {
    __shared__ __align__(16) char smem[32768];
    const int bid   = blockIdx.x;
    const int strip = bid & 31;          // strip's blocks all on XCD strip%8
    const int rbk   = bid >> 5;
    const int tid   = threadIdx.x;
    const int wv    = tid >> 6;
    const int lane  = tid & 63;
    const int col   = lane & 15;
    const int kg    = lane >> 4;
    const int row0  = rbk * ROWS_BLK;

    // A fragments (x rows), resident whole kernel: 8 rg x 2 k-halves.
    bf16x8 a[8][2];
#pragma unroll
    for (int rg = 0; rg < 8; ++rg)
#pragma unroll
        for (int h = 0; h < 2; ++h)
            a[rg][h] = *reinterpret_cast<const bf16x8*>(
                xhi + (size_t)(row0 + rg * 16 + col) * D + h * 32 + kg * 8);

    // staging: LDS linear o <- global (o ^ ((o>>7&7)<<4)).
    const char* wbase = (const char*)whi + (size_t)strip * STRIP_N * 128;
    unsigned soff[8];
#pragma unroll
    for (int i = 0; i < 8; ++i) {
        unsigned o = (unsigned)(i * 256 + tid) * 16;
        soff[i] = o ^ (((o >> 7) & 7u) << 4);
    }

    const unsigned msk = (unsigned)(col & 7) << 4;   // read-side swizzle
    const float* w2s = w2c + strip * STRIP_N;

    float mx[8][4];
#pragma unroll
    for (int rg = 0; rg < 8; ++rg)
#pragma unroll
        for (int r = 0; r < 4; ++r) mx[rg][r] = -3.4e38f;

    for (int p = 0; p < PANELS; ++p) {
        // stage panel p (whole block cooperates, 32 KB)
#pragma unroll
        for (int i = 0; i < 8; ++i)
            gload_lds16(wbase + (size_t)p * 32768 + soff[i],
                        &smem[i * 4096 + wv * 1024]);
        __syncthreads();   // drains vmcnt(0): staging complete for all waves

        const float* w2p = w2s + p * 256;
#pragma unroll
        for (int t = 0; t < 4; ++t) {
            const int nloc = wv * 64 + t * 16 + col;
            const unsigned u0 = (unsigned)nloc * 128 + kg * 16;
            const bf16x8 b0 = *reinterpret_cast<const bf16x8*>(smem + (u0 ^ msk));
            const bf16x8 b1 = *reinterpret_cast<const bf16x8*>(smem + ((u0 + 64) ^ msk));
            const float c = w2p[nloc];
            const f32x4 cq = {c, c, c, c};
#pragma unroll
            for (int rg = 0; rg < 8; ++rg) {
                f32x4 acc = __builtin_amdgcn_mfma_f32_16x16x32_bf16(a[rg][0], b0, cq, 0, 0, 0);
                acc = __builtin_amdgcn_mfma_f32_16x16x32_bf16(a[rg][1], b1, acc, 0, 0, 0);
                mx[rg][0] = fmaxf(mx[rg][0], acc[0]);
                mx[rg][1] = fmaxf(mx[rg][1], acc[1]);
                mx[rg][2] = fmaxf(mx[rg][2], acc[2]);
                mx[rg][3] = fmaxf(mx[rg][3], acc[3]);
            }
        }

        if ((p & 3) == 3) {   // chunk boundary: wave's 256 n done
            const int s = strip * 8 + (p >> 2) * 4 + wv;   // coarse sub id

            if (WRITE_FINE) {  // per-lane fine maxes, no shuffles
                const int f = s * 16 + col;
#pragma unroll
                for (int rg = 0; rg < 8; ++rg) {
                    u16x4 h4 = {bf16up(mx[rg][0]), bf16up(mx[rg][1]),
                                bf16up(mx[rg][2]), bf16up(mx[rg][3])};
                    *reinterpret_cast<u16x4*>(
                        pmf + (size_t)f * B + row0 + rg * 16 + kg * 4) = h4;
                }
            }

#pragma unroll
            for (int rg = 0; rg < 8; ++rg) {
                float v0 = mx[rg][0], v1 = mx[rg][1], v2 = mx[rg][2], v3 = mx[rg][3];
#pragma unroll
                for (int sh = 1; sh < 16; sh <<= 1) {
                    v0 = fmaxf(v0, __shfl_xor(v0, sh, 64));
                    v1 = fmaxf(v1, __shfl_xor(v1, sh, 64));
                    v2 = fmaxf(v2, __shfl_xor(v2, sh, 64));
                    v3 = fmaxf(v3, __shfl_xor(v3, sh, 64));
                }
                float vv = v0;
                vv = (col == 1) ? v1 : vv;
                vv = (col == 2) ? v2 : vv;
                vv = (col == 3) ? v3 : vv;
                if (col < 4)
                    pm[(size_t)(row0 + rg * 16 + kg * 4 + col) * NSUB + s] = vv;
                mx[rg][0] = -3.4e38f; mx[rg][1] = -3.4e38f;
                mx[rg][2] = -3.4e38f; mx[rg][3] = -3.4e38f;
            }
        }
        __syncthreads();   // all waves done reading before next stage
    }
}

// ---- exact fp32 rescore + output (one wave per row) -----------------------
// sub s -> strip = s>>3, chunk = (s>>2)&1, wvv = s&3:
//   base = strip*2048 + chunk*1024 + wvv*64
//   n(p',t,c) = base + p'*256 + t*16 + c   (p' 0..3, t 0..3, c 0..15)
// fine (s,c): j = 0..15 -> n = base + (j>>2)*256 + (j&3)*16 + c
template <int FINE>
__global__ __launch_bounds__(256) void k_rescore(
        const float* __restrict__ x, const float* __restrict__ w,
        const float* __restrict__ w2c, const float* __restrict__ pm,
        const u16* __restrict__ pmf, float* __restrict__ out) {
    const int wv   = threadIdx.x >> 6;
    const int lane = threadIdx.x & 63;
    const int row  = blockIdx.x * 4 + wv;

    float pv[4];
#pragma unroll
    for (int it = 0; it < 4; ++it)
        pv[it] = pm[(size_t)row * NSUB + it * 64 + lane];
    float gm = fmaxf(fmaxf(pv[0], pv[1]), fmaxf(pv[2], pv[3]));
#pragma unroll
    for (int s = 1; s < 64; s <<= 1) gm = fmaxf(gm, __shfl_xor(gm, s, 64));
    const float thr = gm - MARG_HALF;

    const float4* xr = reinterpret_cast<const float4*>(x + (size_t)row * D);
    float4 xq[16];
#pragma unroll
    for (int q = 0; q < 16; ++q) xq[q] = xr[q];

    float bestv = 3.4e38f;
    int   besti = 0x7fffffff;

#pragma unroll
    for (int it = 0; it < 4; ++it) {
        unsigned long long bm = __ballot(pv[it] >= thr);
        while (bm) {
            int sb = __ffsll(bm) - 1;
            bm &= bm - 1;
            int sub  = it * 64 + sb;
            int base = (sub >> 3) * 2048 + ((sub >> 2) & 1) * 1024 + (sub & 3) * 64;

            if (FINE) {
                // 16 fine bf16 (round-up) maxes of this coarse sub
                float fv = -3.4e38f;
                if (lane < 16) {
                    union { unsigned u; float f; } c;
                    c.u = (unsigned)pmf[(size_t)(sub * 16 + lane) * B + row] << 16;
                    fv = c.f;
                }
                unsigned long long fm = __ballot(fv >= thr);   // bits 0..15
                while (fm) {
                    int colq = __ffsll(fm) - 1;
                    fm &= fm - 1;
                    // fine sub n-set: base + (j>>2)*256 + (j&3)*16 + colq
                    int j = lane & 15, q = lane >> 4;
                    int n = base + (j >> 2) * 256 + (j & 3) * 16 + colq;
                    const float4* wr = reinterpret_cast<const float4*>(w + (size_t)n * D);
                    float d0 = 0.f, d1 = 0.f, d2 = 0.f, d3 = 0.f;
#pragma unroll
                    for (int k = 0; k < 4; ++k) {
                        float4 wq = wr[q * 4 + k];
                        float4 xv = xq[q * 4 + k];
                        d0 = fmaf(xv.x, wq.x, d0); d1 = fmaf(xv.y, wq.y, d1);
                        d2 = fmaf(xv.z, wq.z, d2); d3 = fmaf(xv.w, wq.w, d3);
                    }
                    float d = (d0 + d1) + (d2 + d3);
                    d += __shfl_xor(d, 16, 64);
                    d += __shfl_xor(d, 32, 64);      // all 4 copies hold full dot
                    float val = -2.f * (d + w2c[n]);  // == w2 - 2*x.w exact fp32
                    if (val < bestv || (val == bestv && n < besti)) { bestv = val; besti = n; }
                }
            } else {
#pragma unroll
                for (int p4 = 0; p4 < 4; ++p4) {
                    int n = base + p4 * 256 + lane;   // lane = t*16+c
                    const float4* wr = reinterpret_cast<const float4*>(w + (size_t)n * D);
                    float d0 = 0.f, d1 = 0.f, d2 = 0.f, d3 = 0.f;
#pragma unroll
                    for (int q = 0; q < 16; ++q) {
                        float4 wq = wr[q];
                        d0 = fmaf(xq[q].x, wq.x, d0);
                        d1 = fmaf(xq[q].y, wq.y, d1);
                        d2 = fmaf(xq[q].z, wq.z, d2);
                        d3 = fmaf(xq[q].w, wq.w, d3);
                    }
                    float dot = (d0 + d1) + (d2 + d3);
                    float val = -2.f * (dot + w2c[n]);
                    if (val < bestv || (val == bestv && n < besti)) { bestv = val; besti = n; }
                }
            }
        }
    }
#pragma unroll
    for (int s = 1; s < 64; s <<= 1) {
        float ov = __shfl_xor(bestv, s, 64);
        int   oi = __shfl_xor(besti, s, 64);
        if (ov < bestv || (ov == bestv && oi < besti)) { bestv = ov; besti = oi; }
    }
    if (lane == 0) {
        float a0 = 0.f, a1 = 0.f, a2 = 0.f, a3 = 0.f;
#pragma unroll
        for (int q = 0; q < 16; ++q) {
            a0 = fmaf(xq[q].x, xq[q].x, a0);
            a1 = fmaf(xq[q].y, xq[q].y, a1);
            a2 = fmaf(xq[q].z, xq[q].z, a2);
            a3 = fmaf(xq[q].w, xq[q].w, a3);
        }
        float x2 = (a0 + a1) + (a2 + a3);
        float d2f = x2 + bestv;
        if (d2f < 0.f) d2f = 0.f;
        out[row * 2 + 0] = (float)(besti >> 8);    // bmu_y
        out[row * 2 + 1] = (float)(besti & 255);   // bmu_x
        out[2 * B + row] = sqrtf(d2f);
    }
}

// ---- fallback (round-3 proven path, ~1.3 MB ws) ---------------------------
__global__ __launch_bounds__(256) void fb_w2(const float* __restrict__ w,
                                             float* __restrict__ w2) {
    int n = blockIdx.x * 256 + threadIdx.x;
    const float4* wr = reinterpret_cast<const float4*>(w + (size_t)n * D);
    float a0 = 0.f, a1 = 0.f, a2 = 0.f, a3 = 0.f;
#pragma unroll
    for (int q = 0; q < 16; ++q) {
        float4 v = wr[q];
        a0 = fmaf(v.x, v.x, a0); a1 = fmaf(v.y, v.y, a1);
        a2 = fmaf(v.z, v.z, a2); a3 = fmaf(v.w, v.w, a3);
    }
    w2[n] = (a0 + a1) + (a2 + a3);
}

__global__ __launch_bounds__(256) void fb_main(const float* __restrict__ x,
                                               const float* __restrict__ w,
                                               const float* __restrict__ w2,
                                               float* __restrict__ ps,
                                               int* __restrict__ pi) {
    constexpr int NSTRIP = NW / 32;
    const int rb    = blockIdx.x & 15;
    const int strip = blockIdx.x >> 4;
    const int row   = rb * 256 + threadIdx.x;
    float xr[D];
    const float4* xrow = reinterpret_cast<const float4*>(x + (size_t)row * D);
#pragma unroll
    for (int q = 0; q < 16; ++q) {
        float4 v = xrow[q];
        xr[q * 4 + 0] = v.x; xr[q * 4 + 1] = v.y;
        xr[q * 4 + 2] = v.z; xr[q * 4 + 3] = v.w;
    }
    float best = 3.4e38f; int bidx = 0;
    const int n0 = strip * NSTRIP, n1 = n0 + NSTRIP;
    for (int n = n0; n < n1; ++n) {
        const float* wr = w + (size_t)n * D;
        float a0 = 0.f, a1 = 0.f, a2 = 0.f, a3 = 0.f;
#pragma unroll
        for (int d = 0; d < D; d += 4) {
            a0 = fmaf(xr[d + 0], wr[d + 0], a0);
            a1 = fmaf(xr[d + 1], wr[d + 1], a1);
            a2 = fmaf(xr[d + 2], wr[d + 2], a2);
            a3 = fmaf(xr[d + 3], wr[d + 3], a3);
        }
        float s = fmaf(-2.f, (a0 + a1) + (a2 + a3), w2[n]);
        if (s < best) { best = s; bidx = n; }
    }
    ps[(size_t)strip * B + row] = best;
    pi[(size_t)strip * B + row] = bidx;
}

__global__ __launch_bounds__(256) void fb_merge(const float* __restrict__ x,
                                                const float* __restrict__ ps,
                                                const int* __restrict__ pi,
                                                float* __restrict__ out) {
    int row = blockIdx.x * 256 + threadIdx.x;
    float bs = 3.5e38f; int bi = 0;
    for (int t = 0; t < 32; ++t) {
        float s = ps[(size_t)t * B + row];
        int   i = pi[(size_t)t * B + row];
        if (s < bs || (s == bs && i < bi)) { bs = s; bi = i; }
    }
    const float4* xrow = reinterpret_cast<const float4*>(x + (size_t)row * D);
    float a0 = 0.f, a1 = 0.f, a2 = 0.f, a3 = 0.f;
#pragma unroll
    for (int q = 0; q < 16; ++q) {
        float4 v = xrow[q];
        a0 = fmaf(v.x, v.x, a0); a1 = fmaf(v.y, v.y, a1);
        a2 = fmaf(v.z, v.z, a2); a3 = fmaf(v.w, v.w, a3);
    }
    float x2 = (a0 + a1) + (a2 + a3);
    float d2 = x2 + bs;
    if (d2 < 0.f) d2 = 0.f;
    out[row * 2 + 0] = (float)(bi >> 8);
    out[row * 2 + 1] = (float)(bi & 255);
    out[2 * B + row] = sqrtf(d2);
}

// ---------------------------------------------------------------------------
extern "C" void kernel_launch(void* const* d_in, const int* in_sizes, int n_in,
                              void* d_out, int out_size, void* d_ws, size_t ws_size,
                              hipStream_t stream) {
    const float* x = (const float*)d_in[0];   // [B, D]
    const float* w = (const float*)d_in[1];   // [NW, D]
    float* out = (float*)d_out;

    const size_t whi_sz = (size_t)NW * D * 2;        // 8 MB
    const size_t xhi_sz = (size_t)B * D * 2;         // 512 KB
    const size_t w2c_sz = (size_t)NW * 4;            // 256 KB
    const size_t pm_sz  = (size_t)B * NSUB * 4;      // 4 MB
    const size_t pmf_sz = (size_t)NFINE * B * 2;     // 33.5 MB
    const size_t need_c = whi_sz + xhi_sz + w2c_sz + pm_sz;
    const size_t need_f = need_c + pmf_sz;

    if (ws_size >= need_c) {
        char* p = (char*)d_ws;
        u16*   whi = (u16*)p;   p += whi_sz;
        u16*   xhi = (u16*)p;   p += xhi_sz;
        float* w2c = (float*)p; p += w2c_sz;
        float* pm  = (float*)p; p += pm_sz;
        u16*   pmf = (u16*)p;

        k_prep<<<(NW + B) / 256, 256, 0, stream>>>(w, x, whi, xhi, w2c);
        if (ws_size >= need_f) {
            k_screen0<1><<<STRIPS * (B / ROWS_BLK), 256, 0, stream>>>(whi, xhi, w2c, pm, pmf);
            k_rescore<1><<<B / 4, 256, 0, stream>>>(x, w, w2c, pm, pmf, out);
        } else {
            k_screen0<0><<<STRIPS * (B / ROWS_BLK), 256, 0, stream>>>(whi, xhi, w2c, pm, pmf);
            k_rescore<0><<<B / 4, 256, 0, stream>>>(x, w, w2c, pm, pmf, out);
        }
    } else {
        float* w2 = (float*)d_ws;
        float* ps = w2 + NW;
        int*   pi = (int*)(ps + (size_t)32 * B);
        fb_w2<<<NW / 256, 256, 0, stream>>>(w, w2);
        fb_main<<<16 * 32, 256, 0, stream>>>(x, w, w2, ps, pi);
        fb_merge<<<B / 256, 256, 0, stream>>>(x, ps, pi, out);
    }
}

// Round 12
// 124.743 us; speedup vs baseline: 4.2741x; 2.9721x over previous
//
#include <hip/hip_runtime.h>
#include <math.h>

// SOM2dLayer forward: BMU indices + quantization error.
// X[4096,64] f32, W[65536,64] f32 -> out f32: [B*2] (y,x) then [B] qe.
//
// acc'(row,n) = bf16dot(x,w) + w2c[n], w2c = -0.5*sum(w^2); s = -2*acc'.
// min_n s  <=>  max_n acc'.
//   k_prep:    fp32 -> bf16 copies (W and X) + exact w2c
//   k_screen0: bf16 MFMA screen, single 32KB LDS buffer, barrier pipeline.
//              Round-12 fix: __launch_bounds__(256,2) -- the (256,4) bound
//              in r11 clamped VGPR to 64 and spilled ~2KB/thread (FETCH
//              683MB/WRITE 582MB of scratch). With 128 VGPR + 32KB LDS the
//              hardware already fits 4 blocks/CU. Emits:
//                pm [row][256]  exact f32 max per coarse sub (256 n)
//                pmf[fine][row] round-UP bf16 max per fine sub (16 n)
//   k_rescore: thr = max(pm)-MARG; qualifying coarse subs -> fine subs ->
//              exact fp32 rescore (16 n each); argmin, first-index tie-break;
//              qe = sqrt(max(x2+s,0)).
// Round-up bf16 pmf is conservative -> candidate superset, no false
// negatives. No atomics -> deterministic.

typedef short  bf16x8 __attribute__((ext_vector_type(8)));
typedef float  f32x4  __attribute__((ext_vector_type(4)));
typedef unsigned short u16;
typedef unsigned short u16x4 __attribute__((ext_vector_type(4)));

constexpr int D     = 64;
constexpr int NW    = 65536;
constexpr int B     = 4096;
constexpr int NSUB  = 256;             // coarse subs (256 n each)
constexpr int NFINE = NW / 16;         // 4096 fine subs (16 n each)
constexpr float MARG_HALF = 0.15f;     // bf16 screen margin (acc' scale)

constexpr int STRIPS   = 32;
constexpr int STRIP_N  = NW / STRIPS;  // 2048 n per strip = 8 panels of 256
constexpr int PANELS   = 8;
constexpr int ROWS_BLK = 128;

__device__ inline u16 bf16u(float f) {
    union { float f; unsigned u; } v; v.f = f;
    unsigned b = v.u;
    b += 0x7fffu + ((b >> 16) & 1u);   // RNE, finite inputs only
    return (u16)(b >> 16);
}

__device__ inline u16 bf16up(float f) {   // round toward +inf (conservative max)
    union { float f; unsigned u; } v; v.f = f;
    unsigned h = v.u >> 16;
    if ((v.u & 0xFFFFu) && !(v.u >> 31)) h += 1;
    return (u16)h;
}

__device__ __forceinline__ void gload_lds16(const void* g, void* l) {
    __builtin_amdgcn_global_load_lds(
        (const __attribute__((address_space(1))) unsigned int*)g,
        (__attribute__((address_space(3))) unsigned int*)l, 16, 0, 0);
}

// ---- prep: W,X -> bf16 + w2c (fused, one launch) --------------------------
__global__ __launch_bounds__(256) void k_prep(const float* __restrict__ w,
                                              const float* __restrict__ x,
                                              u16* __restrict__ whi,
                                              u16* __restrict__ xhi,
                                              float* __restrict__ w2c) {
    const int idx = blockIdx.x * 256 + threadIdx.x;
    if (idx < NW) {
        const float4* wr = reinterpret_cast<const float4*>(w + (size_t)idx * D);
        u16* orow = whi + (size_t)idx * D;
        float a0 = 0.f, a1 = 0.f, a2 = 0.f, a3 = 0.f;
#pragma unroll
        for (int h = 0; h < 8; ++h) {
            float4 v0 = wr[2 * h], v1 = wr[2 * h + 1];
            a0 = fmaf(v0.x, v0.x, a0); a1 = fmaf(v0.y, v0.y, a1);
            a2 = fmaf(v0.z, v0.z, a2); a3 = fmaf(v0.w, v0.w, a3);
            a0 = fmaf(v1.x, v1.x, a0); a1 = fmaf(v1.y, v1.y, a1);
            a2 = fmaf(v1.z, v1.z, a2); a3 = fmaf(v1.w, v1.w, a3);
            bf16x8 o = {(short)bf16u(v0.x), (short)bf16u(v0.y),
                        (short)bf16u(v0.z), (short)bf16u(v0.w),
                        (short)bf16u(v1.x), (short)bf16u(v1.y),
                        (short)bf16u(v1.z), (short)bf16u(v1.w)};
            *reinterpret_cast<bf16x8*>(orow + 8 * h) = o;
        }
        w2c[idx] = -0.5f * ((a0 + a1) + (a2 + a3));
    } else {
        const int r = idx - NW;
        const float4* xr = reinterpret_cast<const float4*>(x + (size_t)r * D);
        u16* orow = xhi + (size_t)r * D;
#pragma unroll
        for (int h = 0; h < 8; ++h) {
            float4 v0 = xr[2 * h], v1 = xr[2 * h + 1];
            bf16x8 o = {(short)bf16u(v0.x), (short)bf16u(v0.y),
                        (short)bf16u(v0.z), (short)bf16u(v0.w),
                        (short)bf16u(v1.x), (short)bf16u(v1.y),
                        (short)bf16u(v1.z), (short)bf16u(v1.w)};
            *reinterpret_cast<bf16x8*>(orow + 8 * h) = o;
        }
    }
}

// ---- MFMA screen: single-buffer LDS, 4 blocks/CU --------------------------
// Block: 4 waves x 128 rows, strip = 2048 n = 8 panels of 256 n.
// Wave wv computes n-range [wv*64, wv*64+64) of each panel (4 tiles of 16).
// coarse sub s = strip*8 + chunk*4 + wv, chunk = p>>2 (4 panels = 256 n/wave)
// fine sub (s,col): n = strip*2048 + (chunk*4+p')*256 + wv*64 + t*16 + col,
//   j = p'*4 + t  (j = 0..15).
template <int WRITE_FINE>
__global__ __launch_bounds__(256, 2) void k_screen0(
        const u16* __restrict__ whi, const u16* __restrict__ xhi,
        const float* __restrict__ w2c, float* __restrict__ pm,
        u16* __restrict__ pmf) {
    __shared__ __align__(16) char smem[32768];
    const int bid   = blockIdx.x;
    const int strip = bid & 31;          // strip's blocks all on XCD strip%8
    const int rbk   = bid >> 5;
    const int tid   = threadIdx.x;
    const int wv    = tid >> 6;
    const int lane  = tid & 63;
    const int col   = lane & 15;
    const int kg    = lane >> 4;
    const int row0  = rbk * ROWS_BLK;

    // A fragments (x rows), resident whole kernel: 8 rg x 2 k-halves.
    bf16x8 a[8][2];
#pragma unroll
    for (int rg = 0; rg < 8; ++rg)
#pragma unroll
        for (int h = 0; h < 2; ++h)
            a[rg][h] = *reinterpret_cast<const bf16x8*>(
                xhi + (size_t)(row0 + rg * 16 + col) * D + h * 32 + kg * 8);

    // staging: LDS linear o <- global (o ^ ((o>>7&7)<<4)).
    const char* wbase = (const char*)whi + (size_t)strip * STRIP_N * 128;
    unsigned soff[8];
#pragma unroll
    for (int i = 0; i < 8; ++i) {
        unsigned o = (unsigned)(i * 256 + tid) * 16;
        soff[i] = o ^ (((o >> 7) & 7u) << 4);
    }

    const unsigned msk = (unsigned)(col & 7) << 4;   // read-side swizzle
    const float* w2s = w2c + strip * STRIP_N;

    float mx[8][4];
#pragma unroll
    for (int rg = 0; rg < 8; ++rg)
#pragma unroll
        for (int r = 0; r < 4; ++r) mx[rg][r] = -3.4e38f;

    for (int p = 0; p < PANELS; ++p) {
        // stage panel p (whole block cooperates, 32 KB)
#pragma unroll
        for (int i = 0; i < 8; ++i)
            gload_lds16(wbase + (size_t)p * 32768 + soff[i],
                        &smem[i * 4096 + wv * 1024]);
        __syncthreads();   // drains vmcnt(0): staging complete for all waves

        const float* w2p = w2s + p * 256;
#pragma unroll
        for (int t = 0; t < 4; ++t) {
            const int nloc = wv * 64 + t * 16 + col;
            const unsigned u0 = (unsigned)nloc * 128 + kg * 16;
            const bf16x8 b0 = *reinterpret_cast<const bf16x8*>(smem + (u0 ^ msk));
            const bf16x8 b1 = *reinterpret_cast<const bf16x8*>(smem + ((u0 + 64) ^ msk));
            const float c = w2p[nloc];
            const f32x4 cq = {c, c, c, c};
#pragma unroll
            for (int rg = 0; rg < 8; ++rg) {
                f32x4 acc = __builtin_amdgcn_mfma_f32_16x16x32_bf16(a[rg][0], b0, cq, 0, 0, 0);
                acc = __builtin_amdgcn_mfma_f32_16x16x32_bf16(a[rg][1], b1, acc, 0, 0, 0);
                mx[rg][0] = fmaxf(mx[rg][0], acc[0]);
                mx[rg][1] = fmaxf(mx[rg][1], acc[1]);
                mx[rg][2] = fmaxf(mx[rg][2], acc[2]);
                mx[rg][3] = fmaxf(mx[rg][3], acc[3]);
            }
        }

        if ((p & 3) == 3) {   // chunk boundary: wave's 256 n done
            const int s = strip * 8 + (p >> 2) * 4 + wv;   // coarse sub id

            if (WRITE_FINE) {  // per-lane fine maxes, no shuffles
                const int f = s * 16 + col;
#pragma unroll
                for (int rg = 0; rg < 8; ++rg) {
                    u16x4 h4 = {bf16up(mx[rg][0]), bf16up(mx[rg][1]),
                                bf16up(mx[rg][2]), bf16up(mx[rg][3])};
                    *reinterpret_cast<u16x4*>(
                        pmf + (size_t)f * B + row0 + rg * 16 + kg * 4) = h4;
                }
            }

#pragma unroll
            for (int rg = 0; rg < 8; ++rg) {
                float v0 = mx[rg][0], v1 = mx[rg][1], v2 = mx[rg][2], v3 = mx[rg][3];
#pragma unroll
                for (int sh = 1; sh < 16; sh <<= 1) {
                    v0 = fmaxf(v0, __shfl_xor(v0, sh, 64));
                    v1 = fmaxf(v1, __shfl_xor(v1, sh, 64));
                    v2 = fmaxf(v2, __shfl_xor(v2, sh, 64));
                    v3 = fmaxf(v3, __shfl_xor(v3, sh, 64));
                }
                float vv = v0;
                vv = (col == 1) ? v1 : vv;
                vv = (col == 2) ? v2 : vv;
                vv = (col == 3) ? v3 : vv;
                if (col < 4)
                    pm[(size_t)(row0 + rg * 16 + kg * 4 + col) * NSUB + s] = vv;
                mx[rg][0] = -3.4e38f; mx[rg][1] = -3.4e38f;
                mx[rg][2] = -3.4e38f; mx[rg][3] = -3.4e38f;
            }
        }
        __syncthreads();   // all waves done reading before next stage
    }
}

// ---- exact fp32 rescore + output (one wave per row) -----------------------
// sub s -> strip = s>>3, chunk = (s>>2)&1, wvv = s&3:
//   base = strip*2048 + chunk*1024 + wvv*64
//   n(p',t,c) = base + p'*256 + t*16 + c   (p' 0..3, t 0..3, c 0..15)
// fine (s,c): j = 0..15 -> n = base + (j>>2)*256 + (j&3)*16 + c
template <int FINE>
__global__ __launch_bounds__(256) void k_rescore(
        const float* __restrict__ x, const float* __restrict__ w,
        const float* __restrict__ w2c, const float* __restrict__ pm,
        const u16* __restrict__ pmf, float* __restrict__ out) {
    const int wv   = threadIdx.x >> 6;
    const int lane = threadIdx.x & 63;
    const int row  = blockIdx.x * 4 + wv;

    float pv[4];
#pragma unroll
    for (int it = 0; it < 4; ++it)
        pv[it] = pm[(size_t)row * NSUB + it * 64 + lane];
    float gm = fmaxf(fmaxf(pv[0], pv[1]), fmaxf(pv[2], pv[3]));
#pragma unroll
    for (int s = 1; s < 64; s <<= 1) gm = fmaxf(gm, __shfl_xor(gm, s, 64));
    const float thr = gm - MARG_HALF;

    const float4* xr = reinterpret_cast<const float4*>(x + (size_t)row * D);
    float4 xq[16];
#pragma unroll
    for (int q = 0; q < 16; ++q) xq[q] = xr[q];

    float bestv = 3.4e38f;
    int   besti = 0x7fffffff;

#pragma unroll
    for (int it = 0; it < 4; ++it) {
        unsigned long long bm = __ballot(pv[it] >= thr);
        while (bm) {
            int sb = __ffsll(bm) - 1;
            bm &= bm - 1;
            int sub  = it * 64 + sb;
            int base = (sub >> 3) * 2048 + ((sub >> 2) & 1) * 1024 + (sub & 3) * 64;

            if (FINE) {
                // 16 fine bf16 (round-up) maxes of this coarse sub
                float fv = -3.4e38f;
                if (lane < 16) {
                    union { unsigned u; float f; } c;
                    c.u = (unsigned)pmf[(size_t)(sub * 16 + lane) * B + row] << 16;
                    fv = c.f;
                }
                unsigned long long fm = __ballot(fv >= thr);   // bits 0..15
                while (fm) {
                    int colq = __ffsll(fm) - 1;
                    fm &= fm - 1;
                    // fine sub n-set: base + (j>>2)*256 + (j&3)*16 + colq
                    int j = lane & 15, q = lane >> 4;
                    int n = base + (j >> 2) * 256 + (j & 3) * 16 + colq;
                    const float4* wr = reinterpret_cast<const float4*>(w + (size_t)n * D);
                    float d0 = 0.f, d1 = 0.f, d2 = 0.f, d3 = 0.f;
#pragma unroll
                    for (int k = 0; k < 4; ++k) {
                        float4 wq = wr[q * 4 + k];
                        float4 xv = xq[q * 4 + k];
                        d0 = fmaf(xv.x, wq.x, d0); d1 = fmaf(xv.y, wq.y, d1);
                        d2 = fmaf(xv.z, wq.z, d2); d3 = fmaf(xv.w, wq.w, d3);
                    }
                    float d = (d0 + d1) + (d2 + d3);
                    d += __shfl_xor(d, 16, 64);
                    d += __shfl_xor(d, 32, 64);      // all 4 copies hold full dot
                    float val = -2.f * (d + w2c[n]);  // == w2 - 2*x.w exact fp32
                    if (val < bestv || (val == bestv && n < besti)) { bestv = val; besti = n; }
                }
            } else {
#pragma unroll
                for (int p4 = 0; p4 < 4; ++p4) {
                    int n = base + p4 * 256 + lane;   // lane = t*16+c
                    const float4* wr = reinterpret_cast<const float4*>(w + (size_t)n * D);
                    float d0 = 0.f, d1 = 0.f, d2 = 0.f, d3 = 0.f;
#pragma unroll
                    for (int q = 0; q < 16; ++q) {
                        float4 wq = wr[q];
                        d0 = fmaf(xq[q].x, wq.x, d0);
                        d1 = fmaf(xq[q].y, wq.y, d1);
                        d2 = fmaf(xq[q].z, wq.z, d2);
                        d3 = fmaf(xq[q].w, wq.w, d3);
                    }
                    float dot = (d0 + d1) + (d2 + d3);
                    float val = -2.f * (dot + w2c[n]);
                    if (val < bestv || (val == bestv && n < besti)) { bestv = val; besti = n; }
                }
            }
        }
    }
#pragma unroll
    for (int s = 1; s < 64; s <<= 1) {
        float ov = __shfl_xor(bestv, s, 64);
        int   oi = __shfl_xor(besti, s, 64);
        if (ov < bestv || (ov == bestv && oi < besti)) { bestv = ov; besti = oi; }
    }
    if (lane == 0) {
        float a0 = 0.f, a1 = 0.f, a2 = 0.f, a3 = 0.f;
#pragma unroll
        for (int q = 0; q < 16; ++q) {
            a0 = fmaf(xq[q].x, xq[q].x, a0);
            a1 = fmaf(xq[q].y, xq[q].y, a1);
            a2 = fmaf(xq[q].z, xq[q].z, a2);
            a3 = fmaf(xq[q].w, xq[q].w, a3);
        }
        float x2 = (a0 + a1) + (a2 + a3);
        float d2f = x2 + bestv;
        if (d2f < 0.f) d2f = 0.f;
        out[row * 2 + 0] = (float)(besti >> 8);    // bmu_y
        out[row * 2 + 1] = (float)(besti & 255);   // bmu_x
        out[2 * B + row] = sqrtf(d2f);
    }
}

// ---- fallback (round-3 proven path, ~1.3 MB ws) ---------------------------
__global__ __launch_bounds__(256) void fb_w2(const float* __restrict__ w,
                                             float* __restrict__ w2) {
    int n = blockIdx.x * 256 + threadIdx.x;
    const float4* wr = reinterpret_cast<const float4*>(w + (size_t)n * D);
    float a0 = 0.f, a1 = 0.f, a2 = 0.f, a3 = 0.f;
#pragma unroll
    for (int q = 0; q < 16; ++q) {
        float4 v = wr[q];
        a0 = fmaf(v.x, v.x, a0); a1 = fmaf(v.y, v.y, a1);
        a2 = fmaf(v.z, v.z, a2); a3 = fmaf(v.w, v.w, a3);
    }
    w2[n] = (a0 + a1) + (a2 + a3);
}

__global__ __launch_bounds__(256) void fb_main(const float* __restrict__ x,
                                               const float* __restrict__ w,
                                               const float* __restrict__ w2,
                                               float* __restrict__ ps,
                                               int* __restrict__ pi) {
    constexpr int NSTRIP = NW / 32;
    const int rb    = blockIdx.x & 15;
    const int strip = blockIdx.x >> 4;
    const int row   = rb * 256 + threadIdx.x;
    float xr[D];
    const float4* xrow = reinterpret_cast<const float4*>(x + (size_t)row * D);
#pragma unroll
    for (int q = 0; q < 16; ++q) {
        float4 v = xrow[q];
        xr[q * 4 + 0] = v.x; xr[q * 4 + 1] = v.y;
        xr[q * 4 + 2] = v.z; xr[q * 4 + 3] = v.w;
    }
    float best = 3.4e38f; int bidx = 0;
    const int n0 = strip * NSTRIP, n1 = n0 + NSTRIP;
    for (int n = n0; n < n1; ++n) {
        const float* wr = w + (size_t)n * D;
        float a0 = 0.f, a1 = 0.f, a2 = 0.f, a3 = 0.f;
#pragma unroll
        for (int d = 0; d < D; d += 4) {
            a0 = fmaf(xr[d + 0], wr[d + 0], a0);
            a1 = fmaf(xr[d + 1], wr[d + 1], a1);
            a2 = fmaf(xr[d + 2], wr[d + 2], a2);
            a3 = fmaf(xr[d + 3], wr[d + 3], a3);
        }
        float s = fmaf(-2.f, (a0 + a1) + (a2 + a3), w2[n]);
        if (s < best) { best = s; bidx = n; }
    }
    ps[(size_t)strip * B + row] = best;
    pi[(size_t)strip * B + row] = bidx;
}

__global__ __launch_bounds__(256) void fb_merge(const float* __restrict__ x,
                                                const float* __restrict__ ps,
                                                const int* __restrict__ pi,
                                                float* __restrict__ out) {
    int row = blockIdx.x * 256 + threadIdx.x;
    float bs = 3.5e38f; int bi = 0;
    for (int t = 0; t < 32; ++t) {
        float s = ps[(size_t)t * B + row];
        int   i = pi[(size_t)t * B + row];
        if (s < bs || (s == bs && i < bi)) { bs = s; bi = i; }
    }
    const float4* xrow = reinterpret_cast<const float4*>(x + (size_t)row * D);
    float a0 = 0.f, a1 = 0.f, a2 = 0.f, a3 = 0.f;
#pragma unroll
    for (int q = 0; q < 16; ++q) {
        float4 v = xrow[q];
        a0 = fmaf(v.x, v.x, a0); a1 = fmaf(v.y, v.y, a1);
        a2 = fmaf(v.z, v.z, a2); a3 = fmaf(v.w, v.w, a3);
    }
    float x2 = (a0 + a1) + (a2 + a3);
    float d2 = x2 + bs;
    if (d2 < 0.f) d2 = 0.f;
    out[row * 2 + 0] = (float)(bi >> 8);
    out[row * 2 + 1] = (float)(bi & 255);
    out[2 * B + row] = sqrtf(d2);
}

// ---------------------------------------------------------------------------
extern "C" void kernel_launch(void* const* d_in, const int* in_sizes, int n_in,
                              void* d_out, int out_size, void* d_ws, size_t ws_size,
                              hipStream_t stream) {
    const float* x = (const float*)d_in[0];   // [B, D]
    const float* w = (const float*)d_in[1];   // [NW, D]
    float* out = (float*)d_out;

    const size_t whi_sz = (size_t)NW * D * 2;        // 8 MB
    const size_t xhi_sz = (size_t)B * D * 2;         // 512 KB
    const size_t w2c_sz = (size_t)NW * 4;            // 256 KB
    const size_t pm_sz  = (size_t)B * NSUB * 4;      // 4 MB
    const size_t pmf_sz = (size_t)NFINE * B * 2;     // 33.5 MB
    const size_t need_c = whi_sz + xhi_sz + w2c_sz + pm_sz;
    const size_t need_f = need_c + pmf_sz;

    if (ws_size >= need_c) {
        char* p = (char*)d_ws;
        u16*   whi = (u16*)p;   p += whi_sz;
        u16*   xhi = (u16*)p;   p += xhi_sz;
        float* w2c = (float*)p; p += w2c_sz;
        float* pm  = (float*)p; p += pm_sz;
        u16*   pmf = (u16*)p;

        k_prep<<<(NW + B) / 256, 256, 0, stream>>>(w, x, whi, xhi, w2c);
        if (ws_size >= need_f) {
            k_screen0<1><<<STRIPS * (B / ROWS_BLK), 256, 0, stream>>>(whi, xhi, w2c, pm, pmf);
            k_rescore<1><<<B / 4, 256, 0, stream>>>(x, w, w2c, pm, pmf, out);
        } else {
            k_screen0<0><<<STRIPS * (B / ROWS_BLK), 256, 0, stream>>>(whi, xhi, w2c, pm, pmf);
            k_rescore<0><<<B / 4, 256, 0, stream>>>(x, w, w2c, pm, pmf, out);
        }
    } else {
        float* w2 = (float*)d_ws;
        float* ps = w2 + NW;
        int*   pi = (int*)(ps + (size_t)32 * B);
        fb_w2<<<NW / 256, 256, 0, stream>>>(w, w2);
        fb_main<<<16 * 32, 256, 0, stream>>>(x, w, w2, ps, pi);
        fb_merge<<<B / 256, 256, 0, stream>>>(x, ps, pi, out);
    }
}

// Round 13
// 113.434 us; speedup vs baseline: 4.7003x; 1.0997x over previous
//
#include <hip/hip_runtime.h>
#include <math.h>

// SOM2dLayer forward: BMU indices + quantization error.
// X[4096,64] f32, W[65536,64] f32 -> out f32: [B*2] (y,x) then [B] qe.
//
// acc'(row,n) = bf16dot(x,w) + w2c[n], w2c = -0.5*sum(w^2); s = -2*acc'.
// min_n s  <=>  max_n acc'.
//   k_prep:    fp32 -> bf16 copies (W and X) + exact w2c
//   k_screen0: bf16 MFMA screen, single 32KB LDS buffer, barrier pipeline
//              (r12 geometry, proven). Round-13 fix: pm/pmf flushes were
//              SCATTERED stores (8B at 8KB stride -> ~4M sub-line L2
//              transactions) drained by the post-flush __syncthreads vmcnt(0)
//              -- the invariant ~60-75us cost across r7-r12. Now pmf uses a
//              block-linear layout [(sub*32+rbk)][rl][col] and both pm/pmf
//              are staged through LDS, written out fully coalesced.
//   k_rescore: thr = max(pm)-MARG; qualifying coarse subs -> fine subs ->
//              exact fp32 rescore (16 n each); argmin, first-index tie-break;
//              qe = sqrt(max(x2+s,0)). Fine reads now 32B-coalesced.
// Round-up bf16 pmf is conservative -> candidate superset, no false
// negatives. No atomics -> deterministic.

typedef short  bf16x8 __attribute__((ext_vector_type(8)));
typedef float  f32x4  __attribute__((ext_vector_type(4)));
typedef unsigned short u16;

constexpr int D     = 64;
constexpr int NW    = 65536;
constexpr int B     = 4096;
constexpr int NSUB  = 256;             // coarse subs (256 n each)
constexpr int NFINE = NW / 16;         // 4096 fine subs (16 n each)
constexpr float MARG_HALF = 0.15f;     // bf16 screen margin (acc' scale)

constexpr int STRIPS   = 32;
constexpr int STRIP_N  = NW / STRIPS;  // 2048 n per strip = 8 panels of 256
constexpr int PANELS   = 8;
constexpr int ROWS_BLK = 128;

__device__ inline u16 bf16u(float f) {
    union { float f; unsigned u; } v; v.f = f;
    unsigned b = v.u;
    b += 0x7fffu + ((b >> 16) & 1u);   // RNE, finite inputs only
    return (u16)(b >> 16);
}

__device__ inline u16 bf16up(float f) {   // round toward +inf (conservative max)
    union { float f; unsigned u; } v; v.f = f;
    unsigned h = v.u >> 16;
    if ((v.u & 0xFFFFu) && !(v.u >> 31)) h += 1;
    return (u16)h;
}

__device__ __forceinline__ void gload_lds16(const void* g, void* l) {
    __builtin_amdgcn_global_load_lds(
        (const __attribute__((address_space(1))) unsigned int*)g,
        (__attribute__((address_space(3))) unsigned int*)l, 16, 0, 0);
}

// ---- prep: W,X -> bf16 + w2c (fused, one launch) --------------------------
__global__ __launch_bounds__(256) void k_prep(const float* __restrict__ w,
                                              const float* __restrict__ x,
                                              u16* __restrict__ whi,
                                              u16* __restrict__ xhi,
                                              float* __restrict__ w2c) {
    const int idx = blockIdx.x * 256 + threadIdx.x;
    if (idx < NW) {
        const float4* wr = reinterpret_cast<const float4*>(w + (size_t)idx * D);
        u16* orow = whi + (size_t)idx * D;
        float a0 = 0.f, a1 = 0.f, a2 = 0.f, a3 = 0.f;
#pragma unroll
        for (int h = 0; h < 8; ++h) {
            float4 v0 = wr[2 * h], v1 = wr[2 * h + 1];
            a0 = fmaf(v0.x, v0.x, a0); a1 = fmaf(v0.y, v0.y, a1);
            a2 = fmaf(v0.z, v0.z, a2); a3 = fmaf(v0.w, v0.w, a3);
            a0 = fmaf(v1.x, v1.x, a0); a1 = fmaf(v1.y, v1.y, a1);
            a2 = fmaf(v1.z, v1.z, a2); a3 = fmaf(v1.w, v1.w, a3);
            bf16x8 o = {(short)bf16u(v0.x), (short)bf16u(v0.y),
                        (short)bf16u(v0.z), (short)bf16u(v0.w),
                        (short)bf16u(v1.x), (short)bf16u(v1.y),
                        (short)bf16u(v1.z), (short)bf16u(v1.w)};
            *reinterpret_cast<bf16x8*>(orow + 8 * h) = o;
        }
        w2c[idx] = -0.5f * ((a0 + a1) + (a2 + a3));
    } else {
        const int r = idx - NW;
        const float4* xr = reinterpret_cast<const float4*>(x + (size_t)r * D);
        u16* orow = xhi + (size_t)r * D;
#pragma unroll
        for (int h = 0; h < 8; ++h) {
            float4 v0 = xr[2 * h], v1 = xr[2 * h + 1];
            bf16x8 o = {(short)bf16u(v0.x), (short)bf16u(v0.y),
                        (short)bf16u(v0.z), (short)bf16u(v0.w),
                        (short)bf16u(v1.x), (short)bf16u(v1.y),
                        (short)bf16u(v1.z), (short)bf16u(v1.w)};
            *reinterpret_cast<bf16x8*>(orow + 8 * h) = o;
        }
    }
}

// ---- MFMA screen: single-buffer LDS, coalesced LDS-staged flushes ---------
// Block: 4 waves x 128 rows, strip = 2048 n = 8 panels of 256 n.
// Wave wv computes n-range [wv*64, wv*64+64) of each panel (4 tiles of 16).
// coarse sub s = strip*8 + chunk*4 + wv, chunk = p>>2 (4 panels = 256 n/wave)
// fine sub (s,col): j = p'*4 + t (0..15), n = base + (j>>2)*256 + (j&3)*16+col
// pmf layout: [(s*32 + rbk)*2048 + rl*16 + col]  (block-linear, u16)
template <int WRITE_FINE>
__global__ __launch_bounds__(256, 2) void k_screen0(
        const u16* __restrict__ whi, const u16* __restrict__ xhi,
        const float* __restrict__ w2c, float* __restrict__ pm,
        u16* __restrict__ pmf) {
    __shared__ __align__(16) char smem[32768];
    __shared__ __align__(16) float pmsh[512];
    const int bid   = blockIdx.x;
    const int strip = bid & 31;          // strip's blocks all on XCD strip%8
    const int rbk   = bid >> 5;
    const int tid   = threadIdx.x;
    const int wv    = tid >> 6;
    const int lane  = tid & 63;
    const int col   = lane & 15;
    const int kg    = lane >> 4;
    const int row0  = rbk * ROWS_BLK;

    // A fragments (x rows), resident whole kernel: 8 rg x 2 k-halves.
    bf16x8 a[8][2];
#pragma unroll
    for (int rg = 0; rg < 8; ++rg)
#pragma unroll
        for (int h = 0; h < 2; ++h)
            a[rg][h] = *reinterpret_cast<const bf16x8*>(
                xhi + (size_t)(row0 + rg * 16 + col) * D + h * 32 + kg * 8);

    // staging: LDS linear o <- global (o ^ ((o>>7&7)<<4)).
    const char* wbase = (const char*)whi + (size_t)strip * STRIP_N * 128;
    unsigned soff[8];
#pragma unroll
    for (int i = 0; i < 8; ++i) {
        unsigned o = (unsigned)(i * 256 + tid) * 16;
        soff[i] = o ^ (((o >> 7) & 7u) << 4);
    }

    const unsigned msk = (unsigned)(col & 7) << 4;   // read-side swizzle
    const float* w2s = w2c + strip * STRIP_N;

    float mx[8][4];
#pragma unroll
    for (int rg = 0; rg < 8; ++rg)
#pragma unroll
        for (int r = 0; r < 4; ++r) mx[rg][r] = -3.4e38f;

    for (int p = 0; p < PANELS; ++p) {
        // stage panel p (whole block cooperates, 32 KB)
#pragma unroll
        for (int i = 0; i < 8; ++i)
            gload_lds16(wbase + (size_t)p * 32768 + soff[i],
                        &smem[i * 4096 + wv * 1024]);
        __syncthreads();   // staging complete for all waves

        const float* w2p = w2s + p * 256;
#pragma unroll
        for (int t = 0; t < 4; ++t) {
            const int nloc = wv * 64 + t * 16 + col;
            const unsigned u0 = (unsigned)nloc * 128 + kg * 16;
            const bf16x8 b0 = *reinterpret_cast<const bf16x8*>(smem + (u0 ^ msk));
            const bf16x8 b1 = *reinterpret_cast<const bf16x8*>(smem + ((u0 + 64) ^ msk));
            const float c = w2p[nloc];
            const f32x4 cq = {c, c, c, c};
#pragma unroll
            for (int rg = 0; rg < 8; ++rg) {
                f32x4 acc = __builtin_amdgcn_mfma_f32_16x16x32_bf16(a[rg][0], b0, cq, 0, 0, 0);
                acc = __builtin_amdgcn_mfma_f32_16x16x32_bf16(a[rg][1], b1, acc, 0, 0, 0);
                mx[rg][0] = fmaxf(mx[rg][0], acc[0]);
                mx[rg][1] = fmaxf(mx[rg][1], acc[1]);
                mx[rg][2] = fmaxf(mx[rg][2], acc[2]);
                mx[rg][3] = fmaxf(mx[rg][3], acc[3]);
            }
        }

        if ((p & 3) == 3) {   // chunk boundary: wave's 256 n done
            const int s0 = strip * 8 + (p >> 2) * 4;       // first sub of chunk
            const int s  = s0 + wv;                        // this wave's sub

            __syncthreads();   // everyone done reading smem B-data

            if (WRITE_FINE) {  // deposit fine maxes transposed into smem
                u16* st = reinterpret_cast<u16*>(smem);
#pragma unroll
                for (int rg = 0; rg < 8; ++rg)
#pragma unroll
                    for (int r = 0; r < 4; ++r)
                        st[wv * 2048 + (rg * 16 + kg * 4 + r) * 16 + col] =
                            bf16up(mx[rg][r]);
            }

            // coarse max: fold 16 cols -> pmsh[rl*4 + wv]
#pragma unroll
            for (int rg = 0; rg < 8; ++rg) {
                float v0 = mx[rg][0], v1 = mx[rg][1], v2 = mx[rg][2], v3 = mx[rg][3];
#pragma unroll
                for (int sh = 1; sh < 16; sh <<= 1) {
                    v0 = fmaxf(v0, __shfl_xor(v0, sh, 64));
                    v1 = fmaxf(v1, __shfl_xor(v1, sh, 64));
                    v2 = fmaxf(v2, __shfl_xor(v2, sh, 64));
                    v3 = fmaxf(v3, __shfl_xor(v3, sh, 64));
                }
                float vv = v0;
                vv = (col == 1) ? v1 : vv;
                vv = (col == 2) ? v2 : vv;
                vv = (col == 3) ? v3 : vv;
                if (col < 4)
                    pmsh[(rg * 16 + kg * 4 + col) * 4 + wv] = vv;
                mx[rg][0] = -3.4e38f; mx[rg][1] = -3.4e38f;
                mx[rg][2] = -3.4e38f; mx[rg][3] = -3.4e38f;
            }

            __syncthreads();   // staging data visible to all

            // coalesced write-out
            if (WRITE_FINE) {
                const char* src = smem + wv * 4096;
                char* dstg = (char*)pmf + ((size_t)s * 32 + rbk) * 4096;
#pragma unroll
                for (int i = 0; i < 4; ++i)
                    *reinterpret_cast<float4*>(dstg + i * 1024 + lane * 16) =
                        *reinterpret_cast<const float4*>(src + i * 1024 + lane * 16);
            }
            if (tid < 128) {
                float4 v = *reinterpret_cast<const float4*>(&pmsh[tid * 4]);
                *reinterpret_cast<float4*>(&pm[(size_t)(row0 + tid) * NSUB + s0]) = v;
            }
        }
        __syncthreads();   // smem safe to restage
    }
}

// ---- exact fp32 rescore + output (one wave per row) -----------------------
// sub s -> strip = s>>3, chunk = (s>>2)&1, wvv = s&3:
//   base = strip*2048 + chunk*1024 + wvv*64
//   n(p',t,c) = base + p'*256 + t*16 + c   (p' 0..3, t 0..3, c 0..15)
// fine (s,c): j = 0..15 -> n = base + (j>>2)*256 + (j&3)*16 + c
template <int FINE>
__global__ __launch_bounds__(256) void k_rescore(
        const float* __restrict__ x, const float* __restrict__ w,
        const float* __restrict__ w2c, const float* __restrict__ pm,
        const u16* __restrict__ pmf, float* __restrict__ out) {
    const int wv   = threadIdx.x >> 6;
    const int lane = threadIdx.x & 63;
    const int row  = blockIdx.x * 4 + wv;
    const int rbk2 = row >> 7;
    const int rl   = row & 127;

    float pv[4];
#pragma unroll
    for (int it = 0; it < 4; ++it)
        pv[it] = pm[(size_t)row * NSUB + it * 64 + lane];
    float gm = fmaxf(fmaxf(pv[0], pv[1]), fmaxf(pv[2], pv[3]));
#pragma unroll
    for (int s = 1; s < 64; s <<= 1) gm = fmaxf(gm, __shfl_xor(gm, s, 64));
    const float thr = gm - MARG_HALF;

    const float4* xr = reinterpret_cast<const float4*>(x + (size_t)row * D);
    float4 xq[16];
#pragma unroll
    for (int q = 0; q < 16; ++q) xq[q] = xr[q];

    float bestv = 3.4e38f;
    int   besti = 0x7fffffff;

#pragma unroll
    for (int it = 0; it < 4; ++it) {
        unsigned long long bm = __ballot(pv[it] >= thr);
        while (bm) {
            int sb = __ffsll(bm) - 1;
            bm &= bm - 1;
            int sub  = it * 64 + sb;
            int base = (sub >> 3) * 2048 + ((sub >> 2) & 1) * 1024 + (sub & 3) * 64;

            if (FINE) {
                // 16 fine bf16 (round-up) maxes, 32B coalesced
                float fv = -3.4e38f;
                if (lane < 16) {
                    union { unsigned u; float f; } c;
                    c.u = (unsigned)pmf[((size_t)sub * 32 + rbk2) * 2048
                                        + rl * 16 + lane] << 16;
                    fv = c.f;
                }
                unsigned long long fm = __ballot(fv >= thr);   // bits 0..15
                while (fm) {
                    int colq = __ffsll(fm) - 1;
                    fm &= fm - 1;
                    // fine sub n-set: base + (j>>2)*256 + (j&3)*16 + colq
                    int j = lane & 15, q = lane >> 4;
                    int n = base + (j >> 2) * 256 + (j & 3) * 16 + colq;
                    const float4* wr = reinterpret_cast<const float4*>(w + (size_t)n * D);
                    float d0 = 0.f, d1 = 0.f, d2 = 0.f, d3 = 0.f;
#pragma unroll
                    for (int k = 0; k < 4; ++k) {
                        float4 wq = wr[q * 4 + k];
                        float4 xv = xq[q * 4 + k];
                        d0 = fmaf(xv.x, wq.x, d0); d1 = fmaf(xv.y, wq.y, d1);
                        d2 = fmaf(xv.z, wq.z, d2); d3 = fmaf(xv.w, wq.w, d3);
                    }
                    float d = (d0 + d1) + (d2 + d3);
                    d += __shfl_xor(d, 16, 64);
                    d += __shfl_xor(d, 32, 64);      // all 4 copies hold full dot
                    float val = -2.f * (d + w2c[n]);  // == w2 - 2*x.w exact fp32
                    if (val < bestv || (val == bestv && n < besti)) { bestv = val; besti = n; }
                }
            } else {
#pragma unroll
                for (int p4 = 0; p4 < 4; ++p4) {
                    int n = base + p4 * 256 + lane;   // lane = t*16+c
                    const float4* wr = reinterpret_cast<const float4*>(w + (size_t)n * D);
                    float d0 = 0.f, d1 = 0.f, d2 = 0.f, d3 = 0.f;
#pragma unroll
                    for (int q = 0; q < 16; ++q) {
                        float4 wq = wr[q];
                        d0 = fmaf(xq[q].x, wq.x, d0);
                        d1 = fmaf(xq[q].y, wq.y, d1);
                        d2 = fmaf(xq[q].z, wq.z, d2);
                        d3 = fmaf(xq[q].w, wq.w, d3);
                    }
                    float dot = (d0 + d1) + (d2 + d3);
                    float val = -2.f * (dot + w2c[n]);
                    if (val < bestv || (val == bestv && n < besti)) { bestv = val; besti = n; }
                }
            }
        }
    }
#pragma unroll
    for (int s = 1; s < 64; s <<= 1) {
        float ov = __shfl_xor(bestv, s, 64);
        int   oi = __shfl_xor(besti, s, 64);
        if (ov < bestv || (ov == bestv && oi < besti)) { bestv = ov; besti = oi; }
    }
    if (lane == 0) {
        float a0 = 0.f, a1 = 0.f, a2 = 0.f, a3 = 0.f;
#pragma unroll
        for (int q = 0; q < 16; ++q) {
            a0 = fmaf(xq[q].x, xq[q].x, a0);
            a1 = fmaf(xq[q].y, xq[q].y, a1);
            a2 = fmaf(xq[q].z, xq[q].z, a2);
            a3 = fmaf(xq[q].w, xq[q].w, a3);
        }
        float x2 = (a0 + a1) + (a2 + a3);
        float d2f = x2 + bestv;
        if (d2f < 0.f) d2f = 0.f;
        out[row * 2 + 0] = (float)(besti >> 8);    // bmu_y
        out[row * 2 + 1] = (float)(besti & 255);   // bmu_x
        out[2 * B + row] = sqrtf(d2f);
    }
}

// ---- fallback (round-3 proven path, ~1.3 MB ws) ---------------------------
__global__ __launch_bounds__(256) void fb_w2(const float* __restrict__ w,
                                             float* __restrict__ w2) {
    int n = blockIdx.x * 256 + threadIdx.x;
    const float4* wr = reinterpret_cast<const float4*>(w + (size_t)n * D);
    float a0 = 0.f, a1 = 0.f, a2 = 0.f, a3 = 0.f;
#pragma unroll
    for (int q = 0; q < 16; ++q) {
        float4 v = wr[q];
        a0 = fmaf(v.x, v.x, a0); a1 = fmaf(v.y, v.y, a1);
        a2 = fmaf(v.z, v.z, a2); a3 = fmaf(v.w, v.w, a3);
    }
    w2[n] = (a0 + a1) + (a2 + a3);
}

__global__ __launch_bounds__(256) void fb_main(const float* __restrict__ x,
                                               const float* __restrict__ w,
                                               const float* __restrict__ w2,
                                               float* __restrict__ ps,
                                               int* __restrict__ pi) {
    constexpr int NSTRIP = NW / 32;
    const int rb    = blockIdx.x & 15;
    const int strip = blockIdx.x >> 4;
    const int row   = rb * 256 + threadIdx.x;
    float xr[D];
    const float4* xrow = reinterpret_cast<const float4*>(x + (size_t)row * D);
#pragma unroll
    for (int q = 0; q < 16; ++q) {
        float4 v = xrow[q];
        xr[q * 4 + 0] = v.x; xr[q * 4 + 1] = v.y;
        xr[q * 4 + 2] = v.z; xr[q * 4 + 3] = v.w;
    }
    float best = 3.4e38f; int bidx = 0;
    const int n0 = strip * NSTRIP, n1 = n0 + NSTRIP;
    for (int n = n0; n < n1; ++n) {
        const float* wr = w + (size_t)n * D;
        float a0 = 0.f, a1 = 0.f, a2 = 0.f, a3 = 0.f;
#pragma unroll
        for (int d = 0; d < D; d += 4) {
            a0 = fmaf(xr[d + 0], wr[d + 0], a0);
            a1 = fmaf(xr[d + 1], wr[d + 1], a1);
            a2 = fmaf(xr[d + 2], wr[d + 2], a2);
            a3 = fmaf(xr[d + 3], wr[d + 3], a3);
        }
        float s = fmaf(-2.f, (a0 + a1) + (a2 + a3), w2[n]);
        if (s < best) { best = s; bidx = n; }
    }
    ps[(size_t)strip * B + row] = best;
    pi[(size_t)strip * B + row] = bidx;
}

__global__ __launch_bounds__(256) void fb_merge(const float* __restrict__ x,
                                                const float* __restrict__ ps,
                                                const int* __restrict__ pi,
                                                float* __restrict__ out) {
    int row = blockIdx.x * 256 + threadIdx.x;
    float bs = 3.5e38f; int bi = 0;
    for (int t = 0; t < 32; ++t) {
        float s = ps[(size_t)t * B + row];
        int   i = pi[(size_t)t * B + row];
        if (s < bs || (s == bs && i < bi)) { bs = s; bi = i; }
    }
    const float4* xrow = reinterpret_cast<const float4*>(x + (size_t)row * D);
    float a0 = 0.f, a1 = 0.f, a2 = 0.f, a3 = 0.f;
#pragma unroll
    for (int q = 0; q < 16; ++q) {
        float4 v = xrow[q];
        a0 = fmaf(v.x, v.x, a0); a1 = fmaf(v.y, v.y, a1);
        a2 = fmaf(v.z, v.z, a2); a3 = fmaf(v.w, v.w, a3);
    }
    float x2 = (a0 + a1) + (a2 + a3);
    float d2 = x2 + bs;
    if (d2 < 0.f) d2 = 0.f;
    out[row * 2 + 0] = (float)(bi >> 8);
    out[row * 2 + 1] = (float)(bi & 255);
    out[2 * B + row] = sqrtf(d2);
}

// ---------------------------------------------------------------------------
extern "C" void kernel_launch(void* const* d_in, const int* in_sizes, int n_in,
                              void* d_out, int out_size, void* d_ws, size_t ws_size,
                              hipStream_t stream) {
    const float* x = (const float*)d_in[0];   // [B, D]
    const float* w = (const float*)d_in[1];   // [NW, D]
    float* out = (float*)d_out;

    const size_t whi_sz = (size_t)NW * D * 2;        // 8 MB
    const size_t xhi_sz = (size_t)B * D * 2;         // 512 KB
    const size_t w2c_sz = (size_t)NW * 4;            // 256 KB
    const size_t pm_sz  = (size_t)B * NSUB * 4;      // 4 MB
    const size_t pmf_sz = (size_t)NFINE * B * 2;     // 33.5 MB
    const size_t need_c = whi_sz + xhi_sz + w2c_sz + pm_sz;
    const size_t need_f = need_c + pmf_sz;

    if (ws_size >= need_c) {
        char* p = (char*)d_ws;
        u16*   whi = (u16*)p;   p += whi_sz;
        u16*   xhi = (u16*)p;   p += xhi_sz;
        float* w2c = (float*)p; p += w2c_sz;
        float* pm  = (float*)p; p += pm_sz;
        u16*   pmf = (u16*)p;

        k_prep<<<(NW + B) / 256, 256, 0, stream>>>(w, x, whi, xhi, w2c);
        if (ws_size >= need_f) {
            k_screen0<1><<<STRIPS * (B / ROWS_BLK), 256, 0, stream>>>(whi, xhi, w2c, pm, pmf);
            k_rescore<1><<<B / 4, 256, 0, stream>>>(x, w, w2c, pm, pmf, out);
        } else {
            k_screen0<0><<<STRIPS * (B / ROWS_BLK), 256, 0, stream>>>(whi, xhi, w2c, pm, pmf);
            k_rescore<0><<<B / 4, 256, 0, stream>>>(x, w, w2c, pm, pmf, out);
        }
    } else {
        float* w2 = (float*)d_ws;
        float* ps = w2 + NW;
        int*   pi = (int*)(ps + (size_t)32 * B);
        fb_w2<<<NW / 256, 256, 0, stream>>>(w, w2);
        fb_main<<<16 * 32, 256, 0, stream>>>(x, w, w2, ps, pi);
        fb_merge<<<B / 256, 256, 0, stream>>>(x, ps, pi, out);
    }
}